// Round 1
// baseline (929.289 us; speedup 1.0000x reference)
//
#include <hip/hip_runtime.h>
#include <hip/hip_bf16.h>
#include <stdint.h>

#define NC 8192
#define GG 512

typedef __attribute__((ext_vector_type(8))) short bf16x8;   // 8 bf16 = 4 VGPRs (MFMA A/B frag)
typedef __attribute__((ext_vector_type(4))) float fx4;      // MFMA C/D frag
typedef __attribute__((ext_vector_type(4))) unsigned int uint4v;

__device__ __forceinline__ float bf2f(short s){
  union { uint32_t u; float f; } c; c.u = ((uint32_t)(uint16_t)s) << 16; return c.f;
}
__device__ __forceinline__ short f2bf(float f){
  union { float f; uint32_t u; } c; c.f = f;
  uint32_t u = c.u;
  uint32_t r = (u + 0x7fffu + ((u >> 16) & 1u)) >> 16;   // RNE
  return (short)(uint16_t)r;
}
__device__ __forceinline__ uint32_t au(float f){
  union { float f; uint32_t u; } c; c.f = f; return c.u;
}
#if __has_builtin(__builtin_amdgcn_rcpf)
__device__ __forceinline__ float fast_rcp(float x){ return __builtin_amdgcn_rcpf(x); }
#else
__device__ __forceinline__ float fast_rcp(float x){ return 1.0f / x; }
#endif
#if __has_builtin(__builtin_amdgcn_sqrtf)
__device__ __forceinline__ float fast_sqrt(float x){ return __builtin_amdgcn_sqrtf(x); }
#else
__device__ __forceinline__ float fast_sqrt(float x){ return sqrtf(x); }
#endif
__device__ __forceinline__ float tanh_fast(float x){      // |err| ~1e-7 rel of rcp: fine at bf16
  float e = __expf(2.0f * x);
  return 1.0f - 2.0f * fast_rcp(e + 1.0f);
}
// pack two floats -> bf16 pair (round-half-up via +0x8000, then byte-perm hi16s)
__device__ __forceinline__ uint32_t pack_bf(float lo, float hi){
  return __builtin_amdgcn_perm(au(hi) + 0x8000u, au(lo) + 0x8000u, 0x07060302u);
}
__device__ __forceinline__ void g2l16(const void* g, void* l){
  __builtin_amdgcn_global_load_lds((const __attribute__((address_space(1))) void*)g,
                                   (__attribute__((address_space(3))) void*)l, 16, 0, 0);
}

// ---------------- elementwise casts ----------------
__global__ void cast_f32_bf16(const float* __restrict__ in, short* __restrict__ out, int n){
  int i = (blockIdx.x * 256 + threadIdx.x) * 4;
  if (i < n){
    float4 v = *(const float4*)(in + i);
    uint32_t lo = (uint32_t)(uint16_t)f2bf(v.x) | ((uint32_t)(uint16_t)f2bf(v.y) << 16);
    uint32_t hi = (uint32_t)(uint16_t)f2bf(v.z) | ((uint32_t)(uint16_t)f2bf(v.w) << 16);
    *(uint2*)(out + i) = make_uint2(lo, hi);
  }
}

// in f32 [R][C] -> out bf16 at out[c*ostride + roff + r']  (transpose + cast)
// permute!=0: r' permuted within each 32-group to the MFMA k-order
// (j = jt*16+q*4+r -> pos = q*8+jt*4+r) so PV B-frags come straight from QK C-frags.
__global__ void transpose_cast(const float* __restrict__ in, short* __restrict__ out,
                               int R, int C, int ostride, int roff, int permute){
  __shared__ float t[32][33];
  int c0 = blockIdx.x * 32, r0 = blockIdx.y * 32;
  int x = threadIdx.x & 31, y = threadIdx.x >> 5;  // y in 0..7
  #pragma unroll
  for (int it = 0; it < 4; ++it)
    t[y + 8*it][x] = in[(size_t)(r0 + y + 8*it) * C + c0 + x];
  __syncthreads();
  int xp = permute ? (((x >> 2) & 3) * 8 + ((x >> 4) & 1) * 4 + (x & 3)) : x;
  #pragma unroll
  for (int it = 0; it < 4; ++it)
    out[(size_t)(c0 + y + 8*it) * ostride + roff + r0 + xp] = f2bf(t[x][y + 8*it]);
}

__global__ void fill_bias(const float* __restrict__ db1, const float* __restrict__ eb1,
                          const float* __restrict__ qb1, float* __restrict__ b){
  int i = blockIdx.x * 256 + threadIdx.x;
  if (i >= 896) return;
  float v = 0.0f;
  if (i < 512) v = db1[i];
  else if (i < 768) v = eb1[i - 512];
  else if (i < 832) v = qb1[i - 768];
  b[i] = v;
}

// ---------------- GEMM: C[M][N] = A[M][K] @ B[N][K]^T ----------------
// BM=64 BN=128 BK=64, 4 waves as 2x2 of [32m x 64n], 16x16x32 bf16 MFMA.
// modes: 0 = outb = bf16(tanh(c+bias)); 1 = outf = c+bias+res; 3 = outf += scale*c
__global__ __launch_bounds__(256, 2)
void gemm_bt(const short* __restrict__ A, int lda, const short* __restrict__ B, int ldb,
             int K, int mode, const float* __restrict__ bias,
             const float* __restrict__ res, int ldres,
             float* __restrict__ outf, short* __restrict__ outb, int ldo, float scale)
{
  __shared__ __align__(16) short As[64 * 64];
  __shared__ __align__(16) short Bs[128 * 64];
  const int tid = threadIdx.x;
  const int lane = tid & 63, wave = tid >> 6;
  const int wm = wave >> 1, wn = wave & 1;
  const int l16 = lane & 15, q = lane >> 4;
  const size_t i0 = (size_t)blockIdx.y * 64;
  const int n0 = blockIdx.x * 128;
  fx4 acc[2][4] = {};

  for (int k0 = 0; k0 < K; k0 += 64){
    #pragma unroll
    for (int inst = 0; inst < 2; ++inst){              // A tile 64x64 = 8KB
      int ch = inst * 256 + tid;
      int r = ch >> 3, pc = ch & 7;
      int colc = (pc ^ (r & 7)) * 8;
      g2l16(A + (i0 + r) * (size_t)lda + k0 + colc, As + ch * 8);
    }
    #pragma unroll
    for (int inst = 0; inst < 4; ++inst){              // B tile 128x64 = 16KB
      int ch = inst * 256 + tid;
      int r = ch >> 3, pc = ch & 7;
      int colc = (pc ^ (r & 7)) * 8;
      g2l16(B + (size_t)(n0 + r) * (size_t)ldb + k0 + colc, Bs + ch * 8);
    }
    __syncthreads();
    #pragma unroll
    for (int ks = 0; ks < 2; ++ks){
      int k8 = ks * 4 + q;
      bf16x8 af[2], bfr[4];
      #pragma unroll
      for (int mi = 0; mi < 2; ++mi){
        int r = wm * 32 + mi * 16 + l16;
        af[mi] = *(const bf16x8*)(As + r * 64 + ((k8 ^ (r & 7)) << 3));
      }
      #pragma unroll
      for (int ni = 0; ni < 4; ++ni){
        int r = wn * 64 + ni * 16 + l16;
        bfr[ni] = *(const bf16x8*)(Bs + r * 64 + ((k8 ^ (r & 7)) << 3));
      }
      #pragma unroll
      for (int mi = 0; mi < 2; ++mi)
        #pragma unroll
        for (int ni = 0; ni < 4; ++ni)
          acc[mi][ni] = __builtin_amdgcn_mfma_f32_16x16x32_bf16(af[mi], bfr[ni], acc[mi][ni], 0, 0, 0);
    }
    __syncthreads();
  }
  // epilogue: C frag layout col=lane&15 (n), row=q*4+r (m)  [HW-verified R1]
  #pragma unroll
  for (int mi = 0; mi < 2; ++mi){
    #pragma unroll
    for (int ni = 0; ni < 4; ++ni){
      int n = n0 + wn * 64 + ni * 16 + l16;
      float b = bias ? bias[n] : 0.0f;
      #pragma unroll
      for (int r = 0; r < 4; ++r){
        size_t m = i0 + wm * 32 + mi * 16 + q * 4 + r;
        float v = acc[mi][ni][r];
        size_t o = m * (size_t)ldo + n;
        if (mode == 0)      outb[o] = f2bf(tanh_fast(v + b));
        else if (mode == 1) outf[o] = v + b + res[m * (size_t)ldres + n];
        else                outf[o] += v * scale;   // mode 3
      }
    }
  }
}

// ---------------- fused attention, register-resident P, dup=1 wave split ----------------
// 256 threads, 4 waves = 4 DISTINCT 16-row i-slices (IT=64); each wave covers the FULL
// GT g-range -> transform computed exactly once per (i,j) within the block.
// MODE 0 (smooth): P_ij = E_j*exp(-sqrt(max(sq_i+sq_j-2*enc_i.enc_j,0)));
//                  OUT[i][g] = (P@V)/rowsum(P), dual f32 write. V = denoisedT (permuted).
// MODE 1 (heads):  P_ij = sigmoid(Ah_i.enc_j); OUT bf16 [i][z*GG+g]. V = smoothedT (perm).
// j-loop chunks of CH; LDS V double-buffered (2*GT*CH*2 B = 32 KB) -> one barrier/chunk;
// DMA(n+1) + transform(n+1) VALU share the region with PV(n) MFMAs so the scheduler
// interleaves vector-pipe and matrix-pipe work. P never touches memory.
// R1: CH=32 row = 64 B = half the banks; swizzle must fold r>>1 (not r) into the
//     chunk XOR or pv_step's ds_read_b128 is a 4-way bank conflict (6.7e7 cy measured).
//     SH below: slot = (rr&1)*4 + (k8 ^ ((rr>>1)&3)) covers all 8 16B-slots over 8 rows.
// R1: GT=256 for MODE 1 (grid z=4 heads, x=2 g-halves): acc 32->16 fx4 frees ~64 regs,
//     LDS 64->32 KB; target 3 waves/SIMD (was 2).
template<int GT, int CH, int MODE>
__global__ __launch_bounds__(256, 3)
void attn_reg(const short* __restrict__ encA, const short* __restrict__ encJ,
              const short* __restrict__ VTp,
              const float* __restrict__ sq, const float* __restrict__ E,
              float* __restrict__ out0, float* __restrict__ out1,
              short* __restrict__ outb, int ldo)
{
  constexpr int NG  = GT / 16;          // g-tiles per wave
  constexpr int KS  = CH / 32;          // MFMA k-steps per chunk
  constexpr int CPR = CH / 8;           // 16B chunks per LDS row
  constexpr int SH  = (CPR == 4) ? 1 : 0; // bank-spread shift (see note above)
  constexpr int HB  = GT * CH;          // shorts per LDS buffer
  __shared__ __align__(16) short Vl[2 * HB];
  const int tid = threadIdx.x, lane = tid & 63, wave = tid >> 6;
  const int l16 = lane & 15, q = lane >> 4;
  const int i0 = blockIdx.y * 64 + wave * 16;
  const int g0 = blockIdx.x * GT;
  const short* Ai = encA + (size_t)blockIdx.z * NC * 32;

  const bf16x8 bi = *(const bf16x8*)(Ai + (size_t)(i0 + l16) * 32 + q * 8);
  float sqi = 0.f, lacc = 0.f;
  if (MODE == 0) sqi = sq[i0 + l16];
  fx4 acc[NG] = {};
  uint4v bP[KS], bPn[KS];

  auto stage = [&](int jc, int buf){
    #pragma unroll
    for (int inst = 0; inst < HB / 2048; ++inst){
      int ch = inst * 256 + tid;
      int r = ch / CPR, pc = ch % CPR;
      int colc = (pc ^ ((r >> SH) & (CPR - 1))) * 8;
      g2l16(VTp + (size_t)(g0 + r) * NC + jc + colc, Vl + buf * HB + ch * 8);
    }
  };
  auto transform = [&](int jb, uint4v* o){
    #pragma unroll
    for (int ks = 0; ks < KS; ++ks){
      uint32_t dw[4];
      #pragma unroll
      for (int jt = 0; jt < 2; ++jt){
        int j0 = jb + ks * 32 + jt * 16;
        bf16x8 aj = *(const bf16x8*)(encJ + (size_t)(j0 + l16) * 32 + q * 8);
        float4 sqj = {}, Ej = {};
        if (MODE == 0){
          sqj = *(const float4*)(sq + j0 + q * 4);
          Ej  = *(const float4*)(E  + j0 + q * 4);
        }
        fx4 c = {};
        c = __builtin_amdgcn_mfma_f32_16x16x32_bf16(aj, bi, c, 0, 0, 0);
        float pv[4];
        #pragma unroll
        for (int r = 0; r < 4; ++r){
          float dot = c[r];
          if (MODE == 0){
            float d2 = fmaxf(sqi + ((const float*)&sqj)[r] - 2.0f * dot, 0.0f);
            float p = ((const float*)&Ej)[r] * __expf(-fast_sqrt(d2));
            lacc += p;
            pv[r] = p;
          } else {
            pv[r] = fast_rcp(1.0f + __expf(-dot));
          }
        }
        dw[jt * 2]     = pack_bf(pv[0], pv[1]);
        dw[jt * 2 + 1] = pack_bf(pv[2], pv[3]);
      }
      uint4v u = { dw[0], dw[1], dw[2], dw[3] };
      o[ks] = u;
    }
  };
  auto pv_step = [&](int buf){
    #pragma unroll
    for (int ks = 0; ks < KS; ++ks){
      int k8 = ks * 4 + q;
      #pragma unroll
      for (int gt = 0; gt < NG; ++gt){
        int rr = gt * 16 + l16;
        bf16x8 av = *(const bf16x8*)(Vl + buf * HB + rr * CH +
                                     ((k8 ^ ((rr >> SH) & (CPR - 1))) << 3));
        acc[gt] = __builtin_amdgcn_mfma_f32_16x16x32_bf16(
            av, *(const bf16x8*)&bP[ks], acc[gt], 0, 0, 0);
      }
    }
  };

  stage(0, 0);
  transform(0, bP);
  __syncthreads();                       // DMA(0) drained (vmcnt before barrier)
  for (int jc = 0; jc < NC; jc += CH){
    int buf = (jc / CH) & 1;
    int nxt = jc + CH;
    if (nxt < NC){
      stage(nxt, buf ^ 1);               // DMA into other buffer (safe: barrier'd last iter)
      transform(nxt, bPn);               // VALU — interleaves with PV MFMAs below
    }
    pv_step(buf);
    #pragma unroll
    for (int ks = 0; ks < KS; ++ks) bP[ks] = bPn[ks];
    if (nxt < NC) __syncthreads();       // PV(jc) reads done + DMA(nxt) drained
  }

  // epilogue: D frag col = i (l16), row = g (q*4+r)
  if (MODE == 0){
    float v = lacc;                      // reduce over the 4 q-lanes of this i-row
    v += __shfl_xor(v, 16);
    v += __shfl_xor(v, 32);
    float inv = fast_rcp(v);
    #pragma unroll
    for (int gt = 0; gt < NG; ++gt){
      int g = g0 + gt * 16 + q * 4;
      float4 o;
      o.x = acc[gt][0] * inv; o.y = acc[gt][1] * inv;
      o.z = acc[gt][2] * inv; o.w = acc[gt][3] * inv;
      size_t off = (size_t)(i0 + l16) * GG + g;
      *(float4*)(out0 + off) = o;
      *(float4*)(out1 + off) = o;
    }
  } else {
    #pragma unroll
    for (int gt = 0; gt < NG; ++gt){
      int g = g0 + gt * 16 + q * 4;
      uint2 u;
      u.x = pack_bf(acc[gt][0], acc[gt][1]);
      u.y = pack_bf(acc[gt][2], acc[gt][3]);
      *(uint2*)(outb + (size_t)(i0 + l16) * ldo + (size_t)blockIdx.z * GG + g) = u;
    }
  }
}

// ---------------- small MLP tails ----------------
// enc = Hc[:,0:256] @ eW2 + eb2 (bf16-rounded), sq = |enc|^2, Ah[h] = enc @ T[h]
__global__ void embed2_kernel(const short* __restrict__ H2, int lda,
                              const float* __restrict__ eW2,
                              const float* __restrict__ eb2, const float* __restrict__ T4,
                              short* __restrict__ encb, float* __restrict__ sq,
                              short* __restrict__ Ah)
{
  __shared__ float encS[8][32];
  int d = threadIdx.x & 31, cl = threadIdx.x >> 5;
  size_t c = (size_t)blockIdx.x * 8 + cl;
  float s = eb2[d];
  const short* hrow = H2 + c * lda;
  for (int k = 0; k < 256; ++k) s += bf2f(hrow[k]) * eW2[k * 32 + d];
  short eb = f2bf(s);
  encb[c * 32 + d] = eb;
  encS[cl][d] = bf2f(eb);
  __syncthreads();
  if (d == 0){
    float t = 0;
    for (int k = 0; k < 32; ++k) t += encS[cl][k] * encS[cl][k];
    sq[c] = t;
  }
  #pragma unroll
  for (int h = 0; h < 4; ++h){
    float a = 0;
    const float* T = T4 + h * 1024;
    for (int k = 0; k < 32; ++k) a += encS[cl][k] * T[k * 32 + d];
    Ah[(size_t)h * NC * 32 + c * 32 + d] = f2bf(a);
  }
}

// E[c] = exp(Hq[c,:64] . qW2 + qb2)   (tanh already applied by GEMM1)
__global__ void qtail_kernel(const short* __restrict__ Hq, int lda,
                             const float* __restrict__ qW2, const float* __restrict__ qb2,
                             float* __restrict__ E)
{
  int j = threadIdx.x & 63, cl = threadIdx.x >> 6;
  size_t c = (size_t)blockIdx.x * 4 + cl;
  float t = bf2f(Hq[c * lda + j]) * qW2[j];
  #pragma unroll
  for (int o = 32; o >= 1; o >>= 1) t += __shfl_xor(t, o);
  if (j == 0) E[c] = __expf(t + qb2[0]);
}

// ---------------- host ----------------
extern "C" void kernel_launch(void* const* d_in, const int* in_sizes, int n_in,
                              void* d_out, int out_size, void* d_ws, size_t ws_size,
                              hipStream_t stream)
{
  const float* raw = (const float*)d_in[0];
  const float* dW1 = (const float*)d_in[1];
  const float* db1 = (const float*)d_in[2];
  const float* dW2 = (const float*)d_in[3];
  const float* db2 = (const float*)d_in[4];
  const float* eW1 = (const float*)d_in[5];
  const float* eb1 = (const float*)d_in[6];
  const float* eW2 = (const float*)d_in[7];
  const float* eb2 = (const float*)d_in[8];
  const float* qW1 = (const float*)d_in[9];
  const float* qb1 = (const float*)d_in[10];
  const float* qW2 = (const float*)d_in[11];
  const float* qb2 = (const float*)d_in[12];
  const float* Tr  = (const float*)d_in[13];
  const float* Gr  = (const float*)d_in[14];

  float* outD = (float*)d_out;                    // denoised [8192][512]
  float* outS = outD + (size_t)NC * GG;           // smoothed
  float* outF = outS + (size_t)NC * GG;           // final

  char* ws = (char*)d_ws;
  size_t off = 0;
  auto take = [&](size_t bytes) -> char* {
    char* p = ws + off; off += (bytes + 255) & ~(size_t)255; return p;
  };
  short* Xb    = (short*)take((size_t)NC * GG * 2);       // raw bf16
  short* WcatT = (short*)take((size_t)896 * 512 * 2);     // [dW1|eW1|qW1]^T, rows 832..895 pad
  short* dW2T  = (short*)take((size_t)512 * 512 * 2);
  short* GTc   = (short*)take((size_t)512 * 2048 * 2);    // gene_responses^T concat
  float* bcat  = (float*)take((size_t)896 * 4);
  short* Hcat  = (short*)take((size_t)NC * 896 * 2);      // tanh hidden concat [cell][896]
  short* denTp = (short*)take((size_t)GG * NC * 2);       // denoised^T, k-permuted
  short* smoTp = (short*)take((size_t)GG * NC * 2);       // smoothed^T, k-permuted
  short* encb  = (short*)take((size_t)NC * 32 * 2);
  short* Ahb   = (short*)take((size_t)4 * NC * 32 * 2);
  float* sqv   = (float*)take((size_t)NC * 4);
  float* Ev    = (float*)take((size_t)NC * 4);
  short* Ucat  = (short*)take((size_t)NC * 2048 * 2);     // head outputs concat

  dim3 b256(256);
  // ---- casts / transposed weights / bias concat ----
  cast_f32_bf16<<<dim3((NC * GG) / 1024), b256, 0, stream>>>(raw, Xb, NC * GG);
  transpose_cast<<<dim3(16, 16), b256, 0, stream>>>(dW1, WcatT, 512, 512, 512, 0, 0);
  transpose_cast<<<dim3(8, 16),  b256, 0, stream>>>(eW1, WcatT + 512 * 512, 512, 256, 512, 0, 0);
  transpose_cast<<<dim3(2, 16),  b256, 0, stream>>>(qW1, WcatT + 768 * 512, 512, 64, 512, 0, 0);
  transpose_cast<<<dim3(16, 16), b256, 0, stream>>>(dW2, dW2T, 512, 512, 512, 0, 0);
  for (int h = 0; h < 4; ++h)
    transpose_cast<<<dim3(16, 16), b256, 0, stream>>>(Gr + (size_t)h * 512 * 512,
                                                      GTc, 512, 512, 2048, h * 512, 0);
  fill_bias<<<dim3(4), b256, 0, stream>>>(db1, eb1, qb1, bcat);
  // ---- fused first layer: Hcat = tanh(X @ [dW1|eW1|qW1] + bcat)  (N=896) ----
  gemm_bt<<<dim3(7, 128), b256, 0, stream>>>(Xb, 512, WcatT, 512, 512, 0, bcat,
                                             (const float*)nullptr, 0,
                                             (float*)nullptr, Hcat, 896, 1.0f);
  // ---- denoise layer 2: outD = Hcat[:,0:512] @ dW2 + db2 + raw ----
  gemm_bt<<<dim3(4, 128), b256, 0, stream>>>(Hcat, 896, dW2T, 512, 512, 1, db2,
                                             raw, 512, outD, (short*)nullptr, 512, 1.0f);
  transpose_cast<<<dim3(16, 256), b256, 0, stream>>>(outD, denTp, NC, 512, NC, 0, 1);
  // ---- embed tail + quality tail ----
  embed2_kernel<<<dim3(NC / 8), b256, 0, stream>>>(Hcat + 512, 896, eW2, eb2, Tr,
                                                   encb, sqv, Ahb);
  qtail_kernel<<<dim3(NC / 4), b256, 0, stream>>>(Hcat + 768, 896, qW2, qb2, Ev);
  // ---- fused smooth: outS = outF = softmax-weighted avg of denoised (dup=2) ----
  attn_reg<256, 32, 0><<<dim3(2, 128, 1), b256, 0, stream>>>(
      encb, encb, denTp, sqv, Ev, outS, outF, (short*)nullptr, 0);
  transpose_cast<<<dim3(16, 256), b256, 0, stream>>>(outS, smoTp, NC, 512, NC, 0, 1);
  // ---- fused heads: Ucat[:, h*512:] = sigmoid(Ah_h enc^T) @ smoothed (dup=1) ----
  attn_reg<256, 32, 1><<<dim3(2, 128, 4), b256, 0, stream>>>(
      Ahb, encb, smoTp, (const float*)nullptr, (const float*)nullptr,
      (float*)nullptr, (float*)nullptr, Ucat, 2048);
  // ---- final += (Ucat @ GTcat^T) / N   (single K=2048 GEMM) ----
  gemm_bt<<<dim3(4, 128), b256, 0, stream>>>(Ucat, 2048, GTc, 2048, 2048,
                                             3, (const float*)nullptr,
                                             (const float*)nullptr, 0,
                                             outF, (short*)nullptr, 512, 1.0f / NC);
}

// Round 2
// 770.402 us; speedup vs baseline: 1.2062x; 1.2062x over previous
//
#include <hip/hip_runtime.h>
#include <hip/hip_bf16.h>
#include <stdint.h>

#define NC 8192
#define GG 512

typedef __attribute__((ext_vector_type(8))) short bf16x8;   // 8 bf16 = 4 VGPRs (MFMA A/B frag)
typedef __attribute__((ext_vector_type(4))) float fx4;      // MFMA C/D frag
typedef __attribute__((ext_vector_type(4))) unsigned int uint4v;

__device__ __forceinline__ float bf2f(short s){
  union { uint32_t u; float f; } c; c.u = ((uint32_t)(uint16_t)s) << 16; return c.f;
}
__device__ __forceinline__ short f2bf(float f){
  union { float f; uint32_t u; } c; c.f = f;
  uint32_t u = c.u;
  uint32_t r = (u + 0x7fffu + ((u >> 16) & 1u)) >> 16;   // RNE
  return (short)(uint16_t)r;
}
__device__ __forceinline__ uint32_t au(float f){
  union { float f; uint32_t u; } c; c.f = f; return c.u;
}
#if __has_builtin(__builtin_amdgcn_rcpf)
__device__ __forceinline__ float fast_rcp(float x){ return __builtin_amdgcn_rcpf(x); }
#else
__device__ __forceinline__ float fast_rcp(float x){ return 1.0f / x; }
#endif
#if __has_builtin(__builtin_amdgcn_sqrtf)
__device__ __forceinline__ float fast_sqrt(float x){ return __builtin_amdgcn_sqrtf(x); }
#else
__device__ __forceinline__ float fast_sqrt(float x){ return sqrtf(x); }
#endif
__device__ __forceinline__ float tanh_fast(float x){      // |err| ~1e-7 rel of rcp: fine at bf16
  float e = __expf(2.0f * x);
  return 1.0f - 2.0f * fast_rcp(e + 1.0f);
}
// pack two floats -> bf16 pair (round-half-up via +0x8000, then byte-perm hi16s)
__device__ __forceinline__ uint32_t pack_bf(float lo, float hi){
  return __builtin_amdgcn_perm(au(hi) + 0x8000u, au(lo) + 0x8000u, 0x07060302u);
}
__device__ __forceinline__ void g2l16(const void* g, void* l){
  __builtin_amdgcn_global_load_lds((const __attribute__((address_space(1))) void*)g,
                                   (__attribute__((address_space(3))) void*)l, 16, 0, 0);
}

// ---------------- elementwise casts ----------------
__global__ void cast_f32_bf16(const float* __restrict__ in, short* __restrict__ out, int n){
  int i = (blockIdx.x * 256 + threadIdx.x) * 4;
  if (i < n){
    float4 v = *(const float4*)(in + i);
    uint32_t lo = (uint32_t)(uint16_t)f2bf(v.x) | ((uint32_t)(uint16_t)f2bf(v.y) << 16);
    uint32_t hi = (uint32_t)(uint16_t)f2bf(v.z) | ((uint32_t)(uint16_t)f2bf(v.w) << 16);
    *(uint2*)(out + i) = make_uint2(lo, hi);
  }
}

// in f32 [R][C] -> out bf16 at out[c*ostride + roff + r']  (transpose + cast)
// permute!=0: r' permuted within each 32-group to the MFMA k-order
// (j = jt*16+q*4+r -> pos = q*8+jt*4+r) so PV B-frags come straight from QK C-frags.
__global__ void transpose_cast(const float* __restrict__ in, short* __restrict__ out,
                               int R, int C, int ostride, int roff, int permute){
  __shared__ float t[32][33];
  int c0 = blockIdx.x * 32, r0 = blockIdx.y * 32;
  int x = threadIdx.x & 31, y = threadIdx.x >> 5;  // y in 0..7
  #pragma unroll
  for (int it = 0; it < 4; ++it)
    t[y + 8*it][x] = in[(size_t)(r0 + y + 8*it) * C + c0 + x];
  __syncthreads();
  int xp = permute ? (((x >> 2) & 3) * 8 + ((x >> 4) & 1) * 4 + (x & 3)) : x;
  #pragma unroll
  for (int it = 0; it < 4; ++it)
    out[(size_t)(c0 + y + 8*it) * ostride + roff + r0 + xp] = f2bf(t[x][y + 8*it]);
}

__global__ void fill_bias(const float* __restrict__ db1, const float* __restrict__ eb1,
                          const float* __restrict__ qb1, float* __restrict__ b){
  int i = blockIdx.x * 256 + threadIdx.x;
  if (i >= 896) return;
  float v = 0.0f;
  if (i < 512) v = db1[i];
  else if (i < 768) v = eb1[i - 512];
  else if (i < 832) v = qb1[i - 768];
  b[i] = v;
}

// ---------------- GEMM: C[M][N] = A[M][K] @ B[N][K]^T ----------------
// BM=64 BN=128 BK=64, 4 waves as 2x2 of [32m x 64n], 16x16x32 bf16 MFMA.
// modes: 0 = outb = bf16(tanh(c+bias)); 1 = outf = c+bias+res; 3 = outf += scale*c
__global__ __launch_bounds__(256, 2)
void gemm_bt(const short* __restrict__ A, int lda, const short* __restrict__ B, int ldb,
             int K, int mode, const float* __restrict__ bias,
             const float* __restrict__ res, int ldres,
             float* __restrict__ outf, short* __restrict__ outb, int ldo, float scale)
{
  __shared__ __align__(16) short As[64 * 64];
  __shared__ __align__(16) short Bs[128 * 64];
  const int tid = threadIdx.x;
  const int lane = tid & 63, wave = tid >> 6;
  const int wm = wave >> 1, wn = wave & 1;
  const int l16 = lane & 15, q = lane >> 4;
  const size_t i0 = (size_t)blockIdx.y * 64;
  const int n0 = blockIdx.x * 128;
  fx4 acc[2][4] = {};

  for (int k0 = 0; k0 < K; k0 += 64){
    #pragma unroll
    for (int inst = 0; inst < 2; ++inst){              // A tile 64x64 = 8KB
      int ch = inst * 256 + tid;
      int r = ch >> 3, pc = ch & 7;
      int colc = (pc ^ (r & 7)) * 8;
      g2l16(A + (i0 + r) * (size_t)lda + k0 + colc, As + ch * 8);
    }
    #pragma unroll
    for (int inst = 0; inst < 4; ++inst){              // B tile 128x64 = 16KB
      int ch = inst * 256 + tid;
      int r = ch >> 3, pc = ch & 7;
      int colc = (pc ^ (r & 7)) * 8;
      g2l16(B + (size_t)(n0 + r) * (size_t)ldb + k0 + colc, Bs + ch * 8);
    }
    __syncthreads();
    #pragma unroll
    for (int ks = 0; ks < 2; ++ks){
      int k8 = ks * 4 + q;
      bf16x8 af[2], bfr[4];
      #pragma unroll
      for (int mi = 0; mi < 2; ++mi){
        int r = wm * 32 + mi * 16 + l16;
        af[mi] = *(const bf16x8*)(As + r * 64 + ((k8 ^ (r & 7)) << 3));
      }
      #pragma unroll
      for (int ni = 0; ni < 4; ++ni){
        int r = wn * 64 + ni * 16 + l16;
        bfr[ni] = *(const bf16x8*)(Bs + r * 64 + ((k8 ^ (r & 7)) << 3));
      }
      #pragma unroll
      for (int mi = 0; mi < 2; ++mi)
        #pragma unroll
        for (int ni = 0; ni < 4; ++ni)
          acc[mi][ni] = __builtin_amdgcn_mfma_f32_16x16x32_bf16(af[mi], bfr[ni], acc[mi][ni], 0, 0, 0);
    }
    __syncthreads();
  }
  // epilogue: C frag layout col=lane&15 (n), row=q*4+r (m)  [HW-verified R1]
  #pragma unroll
  for (int mi = 0; mi < 2; ++mi){
    #pragma unroll
    for (int ni = 0; ni < 4; ++ni){
      int n = n0 + wn * 64 + ni * 16 + l16;
      float b = bias ? bias[n] : 0.0f;
      #pragma unroll
      for (int r = 0; r < 4; ++r){
        size_t m = i0 + wm * 32 + mi * 16 + q * 4 + r;
        float v = acc[mi][ni][r];
        size_t o = m * (size_t)ldo + n;
        if (mode == 0)      outb[o] = f2bf(tanh_fast(v + b));
        else if (mode == 1) outf[o] = v + b + res[m * (size_t)ldres + n];
        else                outf[o] += v * scale;   // mode 3
      }
    }
  }
}

// ---------------- fused attention, register-resident P ----------------
// 256 threads, 4 waves; each wave owns ISL distinct 16-row i-slices (block = 64*ISL
// i-rows) and the FULL GT g-range.
// MODE 0 (smooth): P_ij = E_j*exp(-sqrt(max(sq_i+sq_j-2*enc_i.enc_j,0)));
//                  OUT[i][g] = (P@V)/rowsum(P), dual f32 write. V = denoisedT (permuted).
// MODE 1 (heads):  P_ij = sigmoid(Ah_i.enc_j); OUT bf16 [i][z*GG+g]. V = smoothedT (perm).
// j-loop chunks of CH; LDS V double-buffered -> one barrier/chunk; DMA(n+1) +
// transform(n+1) VALU overlap PV(n) MFMAs. P never touches memory.
// R2: ISL=2 for MODE 1 -> each 1KB V ds_read_b128 feeds 2 MFMAs (halves LDS-read
//     traffic, the measured ~230us floor of the 404us dispatch); aj shared across
//     slices. acc 2x16 fx4 -> AGPR, ~200 unified regs -> launch_bounds(256,2).
// R2: MODE 0 back to CH=64 (CH=32 regressed ~90us: 2x barriers, worse DMA amort)
//     and GT=128 -> grid 512 blocks (was 256 = 1 blk/CU = 1 wave/SIMD, no latency
//     hiding). NG=8 -> ~88 regs -> launch_bounds(256,4), 16 waves/CU.
// CH=64 swizzle (CPR=8): row = 128B spans all banks; slot = pc ^ (r&7); 16-lane
// frag read hits each slot 2x at 8-row stride = same-bank 2-way = free (m136).
template<int GT, int CH, int MODE, int ISL>
__global__ __launch_bounds__(256, (MODE == 0) ? 4 : 2)
void attn_reg(const short* __restrict__ encA, const short* __restrict__ encJ,
              const short* __restrict__ VTp,
              const float* __restrict__ sq, const float* __restrict__ E,
              float* __restrict__ out0, float* __restrict__ out1,
              short* __restrict__ outb, int ldo)
{
  constexpr int NG  = GT / 16;          // g-tiles per wave
  constexpr int KS  = CH / 32;          // MFMA k-steps per chunk
  constexpr int CPR = CH / 8;           // 16B chunks per LDS row
  constexpr int SH  = (CPR == 4) ? 1 : 0; // bank-spread shift for CH=32 rows
  constexpr int HB  = GT * CH;          // shorts per LDS buffer
  __shared__ __align__(16) short Vl[2 * HB];
  const int tid = threadIdx.x, lane = tid & 63, wave = tid >> 6;
  const int l16 = lane & 15, q = lane >> 4;
  const int ib = blockIdx.y * (64 * ISL) + wave * 16;   // slice s adds s*64
  const int g0 = blockIdx.x * GT;
  const short* Ai = encA + (size_t)blockIdx.z * NC * 32;

  bf16x8 bi[ISL];
  float sqi[ISL], lacc[ISL];
  #pragma unroll
  for (int s = 0; s < ISL; ++s){
    bi[s] = *(const bf16x8*)(Ai + (size_t)(ib + s * 64 + l16) * 32 + q * 8);
    lacc[s] = 0.f;
    sqi[s] = (MODE == 0) ? sq[ib + s * 64 + l16] : 0.f;
  }
  fx4 acc[ISL][NG] = {};
  uint4v bP[ISL][KS], bPn[ISL][KS];

  auto stage = [&](int jc, int buf){
    #pragma unroll
    for (int inst = 0; inst < HB / 2048; ++inst){
      int ch = inst * 256 + tid;
      int r = ch / CPR, pc = ch % CPR;
      int colc = (pc ^ ((r >> SH) & (CPR - 1))) * 8;
      g2l16(VTp + (size_t)(g0 + r) * NC + jc + colc, Vl + buf * HB + ch * 8);
    }
  };
  auto transform = [&](int jb, uint4v (*o)[KS]){
    #pragma unroll
    for (int ks = 0; ks < KS; ++ks){
      uint32_t dw[ISL][4];
      #pragma unroll
      for (int jt = 0; jt < 2; ++jt){
        int j0 = jb + ks * 32 + jt * 16;
        bf16x8 aj = *(const bf16x8*)(encJ + (size_t)(j0 + l16) * 32 + q * 8);
        float4 sqj = {}, Ej = {};
        if (MODE == 0){
          sqj = *(const float4*)(sq + j0 + q * 4);
          Ej  = *(const float4*)(E  + j0 + q * 4);
        }
        #pragma unroll
        for (int s = 0; s < ISL; ++s){
          fx4 c = {};
          c = __builtin_amdgcn_mfma_f32_16x16x32_bf16(aj, bi[s], c, 0, 0, 0);
          float pv[4];
          #pragma unroll
          for (int r = 0; r < 4; ++r){
            float dot = c[r];
            if (MODE == 0){
              float d2 = fmaxf(sqi[s] + ((const float*)&sqj)[r] - 2.0f * dot, 0.0f);
              float p = ((const float*)&Ej)[r] * __expf(-fast_sqrt(d2));
              lacc[s] += p;
              pv[r] = p;
            } else {
              pv[r] = fast_rcp(1.0f + __expf(-dot));
            }
          }
          dw[s][jt * 2]     = pack_bf(pv[0], pv[1]);
          dw[s][jt * 2 + 1] = pack_bf(pv[2], pv[3]);
        }
      }
      #pragma unroll
      for (int s = 0; s < ISL; ++s){
        uint4v u = { dw[s][0], dw[s][1], dw[s][2], dw[s][3] };
        o[s][ks] = u;
      }
    }
  };
  auto pv_step = [&](int buf){
    #pragma unroll
    for (int ks = 0; ks < KS; ++ks){
      int k8 = ks * 4 + q;
      #pragma unroll
      for (int gt = 0; gt < NG; ++gt){
        int rr = gt * 16 + l16;
        bf16x8 av = *(const bf16x8*)(Vl + buf * HB + rr * CH +
                                     ((k8 ^ ((rr >> SH) & (CPR - 1))) << 3));
        #pragma unroll
        for (int s = 0; s < ISL; ++s)
          acc[s][gt] = __builtin_amdgcn_mfma_f32_16x16x32_bf16(
              av, *(const bf16x8*)&bP[s][ks], acc[s][gt], 0, 0, 0);
      }
    }
  };

  stage(0, 0);
  transform(0, bP);
  __syncthreads();                       // DMA(0) drained (vmcnt before barrier)
  for (int jc = 0; jc < NC; jc += CH){
    int buf = (jc / CH) & 1;
    int nxt = jc + CH;
    if (nxt < NC){
      stage(nxt, buf ^ 1);               // DMA into other buffer (safe: barrier'd last iter)
      transform(nxt, bPn);               // VALU — interleaves with PV MFMAs below
    }
    pv_step(buf);
    #pragma unroll
    for (int s = 0; s < ISL; ++s)
      #pragma unroll
      for (int ks = 0; ks < KS; ++ks) bP[s][ks] = bPn[s][ks];
    if (nxt < NC) __syncthreads();       // PV(jc) reads done + DMA(nxt) drained
  }

  // epilogue: D frag col = i (l16), row = g (q*4+r)
  #pragma unroll
  for (int s = 0; s < ISL; ++s){
    int irow = ib + s * 64 + l16;
    if (MODE == 0){
      float v = lacc[s];                 // reduce over the 4 q-lanes of this i-row
      v += __shfl_xor(v, 16);
      v += __shfl_xor(v, 32);
      float inv = fast_rcp(v);
      #pragma unroll
      for (int gt = 0; gt < NG; ++gt){
        int g = g0 + gt * 16 + q * 4;
        float4 o;
        o.x = acc[s][gt][0] * inv; o.y = acc[s][gt][1] * inv;
        o.z = acc[s][gt][2] * inv; o.w = acc[s][gt][3] * inv;
        size_t off = (size_t)irow * GG + g;
        *(float4*)(out0 + off) = o;
        *(float4*)(out1 + off) = o;
      }
    } else {
      #pragma unroll
      for (int gt = 0; gt < NG; ++gt){
        int g = g0 + gt * 16 + q * 4;
        uint2 u;
        u.x = pack_bf(acc[s][gt][0], acc[s][gt][1]);
        u.y = pack_bf(acc[s][gt][2], acc[s][gt][3]);
        *(uint2*)(outb + (size_t)irow * ldo + (size_t)blockIdx.z * GG + g) = u;
      }
    }
  }
}

// ---------------- small MLP tails ----------------
// enc = Hc[:,0:256] @ eW2 + eb2 (bf16-rounded), sq = |enc|^2, Ah[h] = enc @ T[h]
__global__ void embed2_kernel(const short* __restrict__ H2, int lda,
                              const float* __restrict__ eW2,
                              const float* __restrict__ eb2, const float* __restrict__ T4,
                              short* __restrict__ encb, float* __restrict__ sq,
                              short* __restrict__ Ah)
{
  __shared__ float encS[8][32];
  int d = threadIdx.x & 31, cl = threadIdx.x >> 5;
  size_t c = (size_t)blockIdx.x * 8 + cl;
  float s = eb2[d];
  const short* hrow = H2 + c * lda;
  for (int k = 0; k < 256; ++k) s += bf2f(hrow[k]) * eW2[k * 32 + d];
  short eb = f2bf(s);
  encb[c * 32 + d] = eb;
  encS[cl][d] = bf2f(eb);
  __syncthreads();
  if (d == 0){
    float t = 0;
    for (int k = 0; k < 32; ++k) t += encS[cl][k] * encS[cl][k];
    sq[c] = t;
  }
  #pragma unroll
  for (int h = 0; h < 4; ++h){
    float a = 0;
    const float* T = T4 + h * 1024;
    for (int k = 0; k < 32; ++k) a += encS[cl][k] * T[k * 32 + d];
    Ah[(size_t)h * NC * 32 + c * 32 + d] = f2bf(a);
  }
}

// E[c] = exp(Hq[c,:64] . qW2 + qb2)   (tanh already applied by GEMM1)
__global__ void qtail_kernel(const short* __restrict__ Hq, int lda,
                             const float* __restrict__ qW2, const float* __restrict__ qb2,
                             float* __restrict__ E)
{
  int j = threadIdx.x & 63, cl = threadIdx.x >> 6;
  size_t c = (size_t)blockIdx.x * 4 + cl;
  float t = bf2f(Hq[c * lda + j]) * qW2[j];
  #pragma unroll
  for (int o = 32; o >= 1; o >>= 1) t += __shfl_xor(t, o);
  if (j == 0) E[c] = __expf(t + qb2[0]);
}

// ---------------- host ----------------
extern "C" void kernel_launch(void* const* d_in, const int* in_sizes, int n_in,
                              void* d_out, int out_size, void* d_ws, size_t ws_size,
                              hipStream_t stream)
{
  const float* raw = (const float*)d_in[0];
  const float* dW1 = (const float*)d_in[1];
  const float* db1 = (const float*)d_in[2];
  const float* dW2 = (const float*)d_in[3];
  const float* db2 = (const float*)d_in[4];
  const float* eW1 = (const float*)d_in[5];
  const float* eb1 = (const float*)d_in[6];
  const float* eW2 = (const float*)d_in[7];
  const float* eb2 = (const float*)d_in[8];
  const float* qW1 = (const float*)d_in[9];
  const float* qb1 = (const float*)d_in[10];
  const float* qW2 = (const float*)d_in[11];
  const float* qb2 = (const float*)d_in[12];
  const float* Tr  = (const float*)d_in[13];
  const float* Gr  = (const float*)d_in[14];

  float* outD = (float*)d_out;                    // denoised [8192][512]
  float* outS = outD + (size_t)NC * GG;           // smoothed
  float* outF = outS + (size_t)NC * GG;           // final

  char* ws = (char*)d_ws;
  size_t off = 0;
  auto take = [&](size_t bytes) -> char* {
    char* p = ws + off; off += (bytes + 255) & ~(size_t)255; return p;
  };
  short* Xb    = (short*)take((size_t)NC * GG * 2);       // raw bf16
  short* WcatT = (short*)take((size_t)896 * 512 * 2);     // [dW1|eW1|qW1]^T, rows 832..895 pad
  short* dW2T  = (short*)take((size_t)512 * 512 * 2);
  short* GTc   = (short*)take((size_t)512 * 2048 * 2);    // gene_responses^T concat
  float* bcat  = (float*)take((size_t)896 * 4);
  short* Hcat  = (short*)take((size_t)NC * 896 * 2);      // tanh hidden concat [cell][896]
  short* denTp = (short*)take((size_t)GG * NC * 2);       // denoised^T, k-permuted
  short* smoTp = (short*)take((size_t)GG * NC * 2);       // smoothed^T, k-permuted
  short* encb  = (short*)take((size_t)NC * 32 * 2);
  short* Ahb   = (short*)take((size_t)4 * NC * 32 * 2);
  float* sqv   = (float*)take((size_t)NC * 4);
  float* Ev    = (float*)take((size_t)NC * 4);
  short* Ucat  = (short*)take((size_t)NC * 2048 * 2);     // head outputs concat

  dim3 b256(256);
  // ---- casts / transposed weights / bias concat ----
  cast_f32_bf16<<<dim3((NC * GG) / 1024), b256, 0, stream>>>(raw, Xb, NC * GG);
  transpose_cast<<<dim3(16, 16), b256, 0, stream>>>(dW1, WcatT, 512, 512, 512, 0, 0);
  transpose_cast<<<dim3(8, 16),  b256, 0, stream>>>(eW1, WcatT + 512 * 512, 512, 256, 512, 0, 0);
  transpose_cast<<<dim3(2, 16),  b256, 0, stream>>>(qW1, WcatT + 768 * 512, 512, 64, 512, 0, 0);
  transpose_cast<<<dim3(16, 16), b256, 0, stream>>>(dW2, dW2T, 512, 512, 512, 0, 0);
  for (int h = 0; h < 4; ++h)
    transpose_cast<<<dim3(16, 16), b256, 0, stream>>>(Gr + (size_t)h * 512 * 512,
                                                      GTc, 512, 512, 2048, h * 512, 0);
  fill_bias<<<dim3(4), b256, 0, stream>>>(db1, eb1, qb1, bcat);
  // ---- fused first layer: Hcat = tanh(X @ [dW1|eW1|qW1] + bcat)  (N=896) ----
  gemm_bt<<<dim3(7, 128), b256, 0, stream>>>(Xb, 512, WcatT, 512, 512, 0, bcat,
                                             (const float*)nullptr, 0,
                                             (float*)nullptr, Hcat, 896, 1.0f);
  // ---- denoise layer 2: outD = Hcat[:,0:512] @ dW2 + db2 + raw ----
  gemm_bt<<<dim3(4, 128), b256, 0, stream>>>(Hcat, 896, dW2T, 512, 512, 1, db2,
                                             raw, 512, outD, (short*)nullptr, 512, 1.0f);
  transpose_cast<<<dim3(16, 256), b256, 0, stream>>>(outD, denTp, NC, 512, NC, 0, 1);
  // ---- embed tail + quality tail ----
  embed2_kernel<<<dim3(NC / 8), b256, 0, stream>>>(Hcat + 512, 896, eW2, eb2, Tr,
                                                   encb, sqv, Ahb);
  qtail_kernel<<<dim3(NC / 4), b256, 0, stream>>>(Hcat + 768, 896, qW2, qb2, Ev);
  // ---- fused smooth: outS = outF = softmax-weighted avg of denoised ----
  // GT=128 -> 512 blocks (2/CU), 32KB LDS, launch_bounds(256,4): 16 waves/CU
  attn_reg<128, 64, 0, 1><<<dim3(4, 128, 1), b256, 0, stream>>>(
      encb, encb, denTp, sqv, Ev, outS, outF, (short*)nullptr, 0);
  transpose_cast<<<dim3(16, 256), b256, 0, stream>>>(outS, smoTp, NC, 512, NC, 0, 1);
  // ---- fused heads: Ucat[:, h*512:] = sigmoid(Ah_h enc^T) @ smoothed ----
  // ISL=2: block = 128 i-rows, each V frag read feeds 2 MFMAs (halved LDS traffic)
  attn_reg<256, 64, 1, 2><<<dim3(2, 64, 4), b256, 0, stream>>>(
      Ahb, encb, smoTp, (const float*)nullptr, (const float*)nullptr,
      (float*)nullptr, (float*)nullptr, Ucat, 2048);
  // ---- final += (Ucat @ GTcat^T) / N   (single K=2048 GEMM) ----
  gemm_bt<<<dim3(4, 128), b256, 0, stream>>>(Ucat, 2048, GTc, 2048, 2048,
                                             3, (const float*)nullptr,
                                             (const float*)nullptr, 0,
                                             outF, (short*)nullptr, 512, 1.0f / NC);
}